// Round 7
// baseline (1117.231 us; speedup 1.0000x reference)
//
#include <hip/hip_runtime.h>

// 2-layer GRU + FC (B=4096, L=128, IN=16, H=128, NC=24), split into two
// kernels (R6 proved weight-register residency at <=96 frags/wave).
// R7: 512 blocks x 8 batch rows x 512 threads, __launch_bounds__(512,4):
// 2 blocks/CU => 4 waves/SIMD on ALL 256 CUs (R6 ran 2 waves/SIMD and was
// latency-bound at ~2456 cyc/step vs ~550 cyc of issue work). MFMA runs
// M=16 with 8 valid rows (pad rows zeroed; GRU keeps |h|<1 so pads stay
// finite) -- deliberate M-waste to double occupancy.

typedef _Float16 half_t;
typedef _Float16 half8 __attribute__((ext_vector_type(8)));
typedef _Float16 half4v __attribute__((ext_vector_type(4)));
typedef float f32x4 __attribute__((ext_vector_type(4)));

#define HS 136     // padded row stride (halves)
#define XS 520     // x chunk row stride (halves)

static __device__ __forceinline__ f32x4 mfma16(half8 a, half8 b, f32x4 c) {
  return __builtin_amdgcn_mfma_f32_16x16x32_f16(a, b, c, 0, 0, 0);
}

static __device__ __forceinline__ half8 zero8() {
  half8 v;
#pragma unroll
  for (int i = 0; i < 8; ++i) v[i] = (half_t)0.f;
  return v;
}

static __device__ __forceinline__ half8 ldw8(const float* __restrict__ p) {
  float4 a = *(const float4*)p;
  float4 b = *(const float4*)(p + 4);
  half8 r;
  r[0] = (half_t)a.x; r[1] = (half_t)a.y; r[2] = (half_t)a.z; r[3] = (half_t)a.w;
  r[4] = (half_t)b.x; r[5] = (half_t)b.y; r[6] = (half_t)b.z; r[7] = (half_t)b.w;
  return r;
}

static __device__ __forceinline__ float sigm(float v) {
  return __builtin_amdgcn_rcpf(1.f + __expf(-v));
}
static __device__ __forceinline__ float tanh_fast(float v) {
  float e = __expf(2.f * v);
  return 1.f - 2.f * __builtin_amdgcn_rcpf(1.f + e);
}

// ============================ Kernel 1: layer 1 ============================
__global__ __launch_bounds__(512, 4) void gru_l1(
    const float* __restrict__ x,                                    // (4096,2,1024)
    const float* __restrict__ wih1, const float* __restrict__ whh1, // (384,16),(384,128)
    const float* __restrict__ bih1, const float* __restrict__ bhh1,
    half_t* __restrict__ seq1)                                      // (4096,128,128) fp16
{
  __shared__ __align__(16) half_t xl[16][XS];       // 16640 B (rows 8-15 zero)
  __shared__ __align__(16) half_t ost[8][16][HS];   // 34816 B ring, slot t&7

  const int tid = threadIdx.x;
  const int lane = tid & 63;
  const int wv = tid >> 6;
  const int q = lane >> 4;
  const int c = lane & 15;
  const int jc = wv * 16 + c;
  const int s0 = blockIdx.x * 8;

  // zero ring (incl pad rows) and xl pad rows 8-15
  for (int i = tid; i < 8 * 16 * HS; i += 512) ((half_t*)ost)[i] = (half_t)0.f;
  for (int i = tid; i < 8 * XS; i += 512) xl[8 + (i / XS)][i % XS] = (half_t)0.f;

  const float b1r  = bih1[jc]       + bhh1[jc];
  const float b1z  = bih1[128 + jc] + bhh1[128 + jc];
  const float b1in = bih1[256 + jc];
  const float b1hn = bhh1[256 + jc];

  half8 wi1r, wi1z, wi1n;
  if (q < 2) {
    wi1r = ldw8(wih1 + (0 * 128 + jc) * 16 + q * 8);
    wi1z = ldw8(wih1 + (1 * 128 + jc) * 16 + q * 8);
    wi1n = ldw8(wih1 + (2 * 128 + jc) * 16 + q * 8);
  } else {
    wi1r = zero8(); wi1z = zero8(); wi1n = zero8();
  }
  half8 wh1r[4], wh1z[4], wh1n[4];
#pragma unroll
  for (int kk = 0; kk < 4; ++kk) {
    const int ko = kk * 32 + q * 8;
    wh1r[kk] = ldw8(whh1 + (0 * 128 + jc) * 128 + ko);
    wh1z[kk] = ldw8(whh1 + (1 * 128 + jc) * 128 + ko);
    wh1n[kk] = ldw8(whh1 + (2 * 128 + jc) * 128 + ko);
  }

  float h1p[4] = {0.f, 0.f, 0.f, 0.f};
  __syncthreads();

  for (int g = 0; g < 16; ++g) {          // 8-step groups
    if ((g & 3) == 0) {
      const int tc = g >> 2;              // 32-step x chunk
#pragma unroll
      for (int it = 0; it < 2; ++it) {
        int idx = tid + it * 512;         // 0..1023 float4s
        int s = idx >> 7;
        int rem = idx & 127;
        int ch = rem >> 6;
        int i4 = rem & 63;
        const float4 v = *(const float4*)(x + (size_t)(s0 + s) * 2048 + ch * 1024 + tc * 256 + i4 * 4);
        half4v hv;
        hv[0] = (half_t)v.x; hv[1] = (half_t)v.y; hv[2] = (half_t)v.z; hv[3] = (half_t)v.w;
        *(half4v*)&xl[s][(i4 >> 1) * 16 + ch * 8 + (i4 & 1) * 4] = hv;
      }
      __syncthreads();
    }

#pragma unroll
    for (int tt = 0; tt < 8; ++tt) {
      const int t = g * 8 + tt;
      const int prev = (tt + 7) & 7;      // slot of h1[t-1] (static per tt)

      f32x4 ar  = {b1r, b1r, b1r, b1r};
      f32x4 az  = {b1z, b1z, b1z, b1z};
      f32x4 ain = {b1in, b1in, b1in, b1in};
      f32x4 ahn = {b1hn, b1hn, b1hn, b1hn};
      {
        half8 ax = zero8();
        if (q < 2) ax = *(const half8*)&xl[c][(t & 31) * 16 + q * 8];
        ar  = mfma16(ax, wi1r, ar);
        az  = mfma16(ax, wi1z, az);
        ain = mfma16(ax, wi1n, ain);
      }
#pragma unroll
      for (int kk = 0; kk < 4; ++kk) {
        half8 ah = *(const half8*)&ost[prev][c][kk * 32 + q * 8];
        ar  = mfma16(ah, wh1r[kk], ar);
        az  = mfma16(ah, wh1z[kk], az);
        ahn = mfma16(ah, wh1n[kk], ahn);
      }
#pragma unroll
      for (int r = 0; r < 4; ++r) {
        float rg = sigm(ar[r]);
        float zg = sigm(az[r]);
        float ng = tanh_fast(fmaf(rg, ahn[r], ain[r]));
        float hn = fmaf(zg, h1p[r] - ng, ng);
        h1p[r] = hn;
        ost[tt][q * 4 + r][jc] = (half_t)hn;
      }
      __syncthreads();
    }

    // flush group g (slots 0..7 = steps g*8..g*8+7), rows 0..7, 16B units
#pragma unroll
    for (int p = 0; p < 2; ++p) {
      int idx = tid + p * 512;            // 0..1023
      int col16 = idx & 15;
      int row = (idx >> 4) & 7;
      int st = idx >> 7;                  // 0..7
      f32x4 v = *(const f32x4*)&ost[st][row][col16 * 8];
      size_t off = ((size_t)((s0 + row) * 128 + (g * 8 + st))) * 128 + col16 * 8;
      *(f32x4*)(seq1 + off) = v;
    }
    __syncthreads();
  }
}

// ============================ Kernel 2: layer 2 + FC =======================
__global__ __launch_bounds__(512, 4) void gru_l2(
    const half_t* __restrict__ seq1,                                // (4096,128,128) fp16
    const float* __restrict__ wih2, const float* __restrict__ whh2, // (384,128)x2
    const float* __restrict__ bih2, const float* __restrict__ bhh2,
    const float* __restrict__ fcw, const float* __restrict__ fcb,   // (24,128),(24,)
    float* __restrict__ out)                                        // (4096,24)
{
  __shared__ __align__(16) half_t sc[2][4][16][HS];  // 34816 B (4-step chunks)
  __shared__ __align__(16) half_t h2b[2][16][HS];    //  8704 B
  __shared__ float h2f[8][132];                      //  4224 B

  const int tid = threadIdx.x;
  const int lane = tid & 63;
  const int wv = tid >> 6;
  const int q = lane >> 4;
  const int c = lane & 15;
  const int jc = wv * 16 + c;
  const int s0 = blockIdx.x * 8;

  // zero everything once (pads stay zero; h2b[0] is the t=-1 state)
  for (int i = tid; i < 2 * 4 * 16 * HS; i += 512) ((half_t*)sc)[i] = (half_t)0.f;
  for (int i = tid; i < 2 * 16 * HS; i += 512) ((half_t*)h2b)[i] = (half_t)0.f;

  const float b2r  = bih2[jc]       + bhh2[jc];
  const float b2z  = bih2[128 + jc] + bhh2[128 + jc];
  const float b2in = bih2[256 + jc];
  const float b2hn = bhh2[256 + jc];

  half8 wi2r[4], wi2z[4], wi2n[4], wh2r[4], wh2z[4], wh2n[4];
#pragma unroll
  for (int kk = 0; kk < 4; ++kk) {
    const int ko = kk * 32 + q * 8;
    wi2r[kk] = ldw8(wih2 + (0 * 128 + jc) * 128 + ko);
    wi2z[kk] = ldw8(wih2 + (1 * 128 + jc) * 128 + ko);
    wi2n[kk] = ldw8(wih2 + (2 * 128 + jc) * 128 + ko);
    wh2r[kk] = ldw8(whh2 + (0 * 128 + jc) * 128 + ko);
    wh2z[kk] = ldw8(whh2 + (1 * 128 + jc) * 128 + ko);
    wh2n[kk] = ldw8(whh2 + (2 * 128 + jc) * 128 + ko);
  }
  __syncthreads();

  // preload chunk 0 (steps 0..3): 512 threads = 4 st x 8 rows x 16 col16
  {
    const int col16 = tid & 15;
    const int row = (tid >> 4) & 7;
    const int st = tid >> 7;              // 0..3
    size_t off = ((size_t)((s0 + row) * 128 + st)) * 128 + col16 * 8;
    *(f32x4*)&sc[0][st][row][col16 * 8] = *(const f32x4*)(seq1 + off);
  }
  __syncthreads();

  float h2p[4] = {0.f, 0.f, 0.f, 0.f};
  const int col16 = tid & 15;
  const int prow = (tid >> 4) & 7;
  const int pst = tid >> 7;

  for (int ch = 0; ch < 32; ++ch) {       // 32 chunks x 4 steps
    f32x4 pf;
    if (ch < 31) {
      size_t off = ((size_t)((s0 + prow) * 128 + ((ch + 1) * 4 + pst))) * 128 + col16 * 8;
      pf = *(const f32x4*)(seq1 + off);
    }
    const int cb = ch & 1;

#pragma unroll
    for (int tt = 0; tt < 4; ++tt) {
      const int rb = tt & 1;              // step i = ch*4+tt; i&1 == tt&1
      const int wb = rb ^ 1;

      f32x4 cr  = {b2r, b2r, b2r, b2r};
      f32x4 cz  = {b2z, b2z, b2z, b2z};
      f32x4 cin = {b2in, b2in, b2in, b2in};
      f32x4 chn = {b2hn, b2hn, b2hn, b2hn};
#pragma unroll
      for (int kk = 0; kk < 4; ++kk) {
        half8 a1 = *(const half8*)&sc[cb][tt][c][kk * 32 + q * 8];  // h1[i]
        half8 a2 = *(const half8*)&h2b[rb][c][kk * 32 + q * 8];     // h2[i-1]
        cr  = mfma16(a1, wi2r[kk], cr);
        cz  = mfma16(a1, wi2z[kk], cz);
        cin = mfma16(a1, wi2n[kk], cin);
        cr  = mfma16(a2, wh2r[kk], cr);
        cz  = mfma16(a2, wh2z[kk], cz);
        chn = mfma16(a2, wh2n[kk], chn);
      }
#pragma unroll
      for (int r = 0; r < 4; ++r) {
        float rg = sigm(cr[r]);
        float zg = sigm(cz[r]);
        float ng = tanh_fast(fmaf(rg, chn[r], cin[r]));
        float hn = fmaf(zg, h2p[r] - ng, ng);
        h2p[r] = hn;
        h2b[wb][q * 4 + r][jc] = (half_t)hn;
      }
      if (tt == 3 && ch < 31) {           // commit prefetched chunk
        *(f32x4*)&sc[cb ^ 1][pst][prow][col16 * 8] = pf;
      }
      __syncthreads();
    }
  }

  // FC epilogue (fp32)
  if (q < 2) {
#pragma unroll
    for (int r = 0; r < 4; ++r) h2f[q * 4 + r][jc] = h2p[r];
  }
  __syncthreads();
  if (tid < 192) {
    const int m = tid & 7;
    const int cls = tid >> 3;             // 0..23
    const float* w = fcw + cls * 128;
    float acc = fcb[cls];
#pragma unroll 8
    for (int j = 0; j < 128; ++j) acc = fmaf(h2f[m][j], w[j], acc);
    out[(size_t)(s0 + m) * 24 + cls] = acc;
  }
}

// ===================== Fallback: round-3 fused kernel ======================
__global__ __launch_bounds__(512, 2) void gru_fused(
    const float* __restrict__ x,
    const float* __restrict__ wih1, const float* __restrict__ whh1,
    const float* __restrict__ bih1, const float* __restrict__ bhh1,
    const float* __restrict__ wih2, const float* __restrict__ whh2,
    const float* __restrict__ bih2, const float* __restrict__ bhh2,
    const float* __restrict__ fcw, const float* __restrict__ fcb,
    float* __restrict__ out)
{
  __shared__ __align__(16) half_t xl[16][XS];
  __shared__ __align__(16) half_t h1b[2][16][HS];
  __shared__ __align__(16) half_t h2b[2][16][HS];
  __shared__ float h2f[16][129];

  const int tid = threadIdx.x;
  const int lane = tid & 63;
  const int wv = tid >> 6;
  const int q = lane >> 4;
  const int c = lane & 15;
  const int jc = wv * 16 + c;
  const int s0 = blockIdx.x * 16;

  for (int i = tid; i < 2 * 16 * HS; i += 512) {
    ((half_t*)h1b)[i] = (half_t)0.f;
    ((half_t*)h2b)[i] = (half_t)0.f;
  }

  const float b1r  = bih1[jc]       + bhh1[jc];
  const float b1z  = bih1[128 + jc] + bhh1[128 + jc];
  const float b1in = bih1[256 + jc];
  const float b1hn = bhh1[256 + jc];
  const float b2r  = bih2[jc]       + bhh2[jc];
  const float b2z  = bih2[128 + jc] + bhh2[128 + jc];
  const float b2in = bih2[256 + jc];
  const float b2hn = bhh2[256 + jc];

  half8 wi1r, wi1z, wi1n;
  if (q < 2) {
    wi1r = ldw8(wih1 + (0 * 128 + jc) * 16 + q * 8);
    wi1z = ldw8(wih1 + (1 * 128 + jc) * 16 + q * 8);
    wi1n = ldw8(wih1 + (2 * 128 + jc) * 16 + q * 8);
  } else {
    wi1r = zero8(); wi1z = zero8(); wi1n = zero8();
  }
  half8 wh1r[4], wh1z[4], wh1n[4], wi2r[4], wi2z[4], wi2n[4], wh2r[4], wh2z[4], wh2n[4];
#pragma unroll
  for (int kk = 0; kk < 4; ++kk) {
    const int ko = kk * 32 + q * 8;
    wh1r[kk] = ldw8(whh1 + (0 * 128 + jc) * 128 + ko);
    wh1z[kk] = ldw8(whh1 + (1 * 128 + jc) * 128 + ko);
    wh1n[kk] = ldw8(whh1 + (2 * 128 + jc) * 128 + ko);
    wi2r[kk] = ldw8(wih2 + (0 * 128 + jc) * 128 + ko);
    wi2z[kk] = ldw8(wih2 + (1 * 128 + jc) * 128 + ko);
    wi2n[kk] = ldw8(wih2 + (2 * 128 + jc) * 128 + ko);
    wh2r[kk] = ldw8(whh2 + (0 * 128 + jc) * 128 + ko);
    wh2z[kk] = ldw8(whh2 + (1 * 128 + jc) * 128 + ko);
    wh2n[kk] = ldw8(whh2 + (2 * 128 + jc) * 128 + ko);
  }

  float h1p[4] = {0.f, 0.f, 0.f, 0.f};
  float h2p[4] = {0.f, 0.f, 0.f, 0.f};

  for (int tc = 0; tc < 4; ++tc) {
#pragma unroll
    for (int it = 0; it < 4; ++it) {
      int idx = tid + it * 512;
      int s = idx >> 7;
      int rem = idx & 127;
      int ch = rem >> 6;
      int i4 = rem & 63;
      const float4 v = *(const float4*)(x + (size_t)(s0 + s) * 2048 + ch * 1024 + tc * 256 + i4 * 4);
      half4v hv;
      hv[0] = (half_t)v.x; hv[1] = (half_t)v.y; hv[2] = (half_t)v.z; hv[3] = (half_t)v.w;
      *(half4v*)&xl[s][(i4 >> 1) * 16 + ch * 8 + (i4 & 1) * 4] = hv;
    }
    __syncthreads();

    for (int tt = 0; tt < 32; ++tt) {
      const int i = tc * 32 + tt;
      const int rb = i & 1;
      const int wb = rb ^ 1;

      f32x4 ar  = {b1r, b1r, b1r, b1r};
      f32x4 az  = {b1z, b1z, b1z, b1z};
      f32x4 ain = {b1in, b1in, b1in, b1in};
      f32x4 ahn = {b1hn, b1hn, b1hn, b1hn};
      f32x4 cr  = {b2r, b2r, b2r, b2r};
      f32x4 cz  = {b2z, b2z, b2z, b2z};
      f32x4 cin = {b2in, b2in, b2in, b2in};
      f32x4 chn = {b2hn, b2hn, b2hn, b2hn};

      {
        half8 ax = zero8();
        if (q < 2) ax = *(const half8*)&xl[c][tt * 16 + q * 8];
        ar  = mfma16(ax, wi1r, ar);
        az  = mfma16(ax, wi1z, az);
        ain = mfma16(ax, wi1n, ain);
      }
#pragma unroll
      for (int kk = 0; kk < 4; ++kk) {
        half8 ah = *(const half8*)&h1b[rb][c][kk * 32 + q * 8];
        half8 a2 = *(const half8*)&h2b[rb][c][kk * 32 + q * 8];
        ar  = mfma16(ah, wh1r[kk], ar);
        az  = mfma16(ah, wh1z[kk], az);
        ahn = mfma16(ah, wh1n[kk], ahn);
        cr  = mfma16(ah, wi2r[kk], cr);
        cz  = mfma16(ah, wi2z[kk], cz);
        cin = mfma16(ah, wi2n[kk], cin);
        cr  = mfma16(a2, wh2r[kk], cr);
        cz  = mfma16(a2, wh2z[kk], cz);
        chn = mfma16(a2, wh2n[kk], chn);
      }

#pragma unroll
      for (int r = 0; r < 4; ++r) {
        float rg = sigm(ar[r]);
        float zg = sigm(az[r]);
        float ng = tanh_fast(fmaf(rg, ahn[r], ain[r]));
        float hn = fmaf(zg, h1p[r] - ng, ng);
        h1p[r] = hn;
        h1b[wb][q * 4 + r][jc] = (half_t)hn;
      }
      if (i > 0) {
#pragma unroll
        for (int r = 0; r < 4; ++r) {
          float rg = sigm(cr[r]);
          float zg = sigm(cz[r]);
          float ng = tanh_fast(fmaf(rg, chn[r], cin[r]));
          float hn = fmaf(zg, h2p[r] - ng, ng);
          h2p[r] = hn;
          h2b[wb][q * 4 + r][jc] = (half_t)hn;
        }
      }
      __syncthreads();
    }
  }

  {
    f32x4 cr  = {b2r, b2r, b2r, b2r};
    f32x4 cz  = {b2z, b2z, b2z, b2z};
    f32x4 cin = {b2in, b2in, b2in, b2in};
    f32x4 chn = {b2hn, b2hn, b2hn, b2hn};
#pragma unroll
    for (int kk = 0; kk < 4; ++kk) {
      half8 a1 = *(const half8*)&h1b[0][c][kk * 32 + q * 8];
      half8 a2 = *(const half8*)&h2b[0][c][kk * 32 + q * 8];
      cr  = mfma16(a1, wi2r[kk], cr);
      cz  = mfma16(a1, wi2z[kk], cz);
      cin = mfma16(a1, wi2n[kk], cin);
      cr  = mfma16(a2, wh2r[kk], cr);
      cz  = mfma16(a2, wh2z[kk], cz);
      chn = mfma16(a2, wh2n[kk], chn);
    }
#pragma unroll
    for (int r = 0; r < 4; ++r) {
      float rg = sigm(cr[r]);
      float zg = sigm(cz[r]);
      float ng = tanh_fast(fmaf(rg, chn[r], cin[r]));
      h2p[r] = fmaf(zg, h2p[r] - ng, ng);
    }
  }

#pragma unroll
  for (int r = 0; r < 4; ++r) h2f[q * 4 + r][jc] = h2p[r];
  __syncthreads();
  if (tid < 384) {
    const int m = tid & 15;
    const int cls = tid >> 4;
    const float* w = fcw + cls * 128;
    float acc = fcb[cls];
#pragma unroll 8
    for (int j = 0; j < 128; ++j) acc = fmaf(h2f[m][j], w[j], acc);
    out[(size_t)(s0 + m) * 24 + cls] = acc;
  }
}

extern "C" void kernel_launch(void* const* d_in, const int* in_sizes, int n_in,
                              void* d_out, int out_size, void* d_ws, size_t ws_size,
                              hipStream_t stream) {
  (void)in_sizes; (void)n_in; (void)out_size;
  const float* x    = (const float*)d_in[0];
  const float* wih1 = (const float*)d_in[1];
  const float* whh1 = (const float*)d_in[2];
  const float* bih1 = (const float*)d_in[3];
  const float* bhh1 = (const float*)d_in[4];
  const float* wih2 = (const float*)d_in[5];
  const float* whh2 = (const float*)d_in[6];
  const float* bih2 = (const float*)d_in[7];
  const float* bhh2 = (const float*)d_in[8];
  const float* fcw  = (const float*)d_in[9];
  const float* fcb  = (const float*)d_in[10];
  float* outp = (float*)d_out;

  const size_t seq_bytes = (size_t)4096 * 128 * 128 * sizeof(half_t);  // 128 MiB
  if (ws_size >= seq_bytes) {
    half_t* seq1 = (half_t*)d_ws;
    gru_l1<<<dim3(512), dim3(512), 0, stream>>>(x, wih1, whh1, bih1, bhh1, seq1);
    gru_l2<<<dim3(512), dim3(512), 0, stream>>>(seq1, wih2, whh2, bih2, bhh2, fcw, fcb, outp);
  } else {
    gru_fused<<<dim3(256), dim3(512), 0, stream>>>(
        x, wih1, whh1, bih1, bhh1, wih2, whh2, bih2, bhh2, fcw, fcb, outp);
  }
}

// Round 8
// 492.365 us; speedup vs baseline: 2.2691x; 2.2691x over previous
//
#include <hip/hip_runtime.h>

// 2-layer GRU + FC (B=4096, L=128, IN=16, H=128, NC=24), two kernels, each
// with PRODUCER/CONSUMER wave specialization:
//   producers (waves 8..15): hold W_ih only (<=48 regs), compute the input
//     projection xp[i] one step AHEAD of the scan (no recurrence dep),
//     into an LDS ring in exactly the consumer's MFMA C/D lane layout.
//   consumers (waves 0..7): hold W_hh only (48 regs), run the serial scan:
//     h-frags from LDS ring -> 12 MFMAs -> gates(+xp) -> write h.
// Every wave <= ~110 regs  =>  fits the 128-reg cap of 4 waves/SIMD
// (1024 thr, 16 waves, 1 block/CU, 256 blocks). R6 proved 96-reg waves only
// fit at 2 waves/SIMD (latency convoy, 2456 cyc/step); R7 proved 96-reg
// waves at 4 waves/SIMD collapse to global weight refetch (2.8 GB FETCH).
// Both roles share ONE weight-array declaration (base = prod? w_ih : w_hh)
// so register allocation takes max(role), not sum.

typedef _Float16 half_t;
typedef _Float16 half8 __attribute__((ext_vector_type(8)));
typedef _Float16 half4v __attribute__((ext_vector_type(4)));
typedef float f32x4 __attribute__((ext_vector_type(4)));

#define HS 136     // padded h row stride (halves)
#define XS 520     // x chunk row stride (halves)

static __device__ __forceinline__ f32x4 mfma16(half8 a, half8 b, f32x4 c) {
  return __builtin_amdgcn_mfma_f32_16x16x32_f16(a, b, c, 0, 0, 0);
}

static __device__ __forceinline__ half8 zero8() {
  half8 v;
#pragma unroll
  for (int i = 0; i < 8; ++i) v[i] = (half_t)0.f;
  return v;
}

static __device__ __forceinline__ half8 ldw8(const float* __restrict__ p) {
  float4 a = *(const float4*)p;
  float4 b = *(const float4*)(p + 4);
  half8 r;
  r[0] = (half_t)a.x; r[1] = (half_t)a.y; r[2] = (half_t)a.z; r[3] = (half_t)a.w;
  r[4] = (half_t)b.x; r[5] = (half_t)b.y; r[6] = (half_t)b.z; r[7] = (half_t)b.w;
  return r;
}

static __device__ __forceinline__ float sigm(float v) {
  return __builtin_amdgcn_rcpf(1.f + __expf(-v));
}
static __device__ __forceinline__ float tanh_fast(float v) {
  float e = __expf(2.f * v);
  return 1.f - 2.f * __builtin_amdgcn_rcpf(1.f + e);
}

// ============================ Kernel 1: layer 1 ============================
__global__ __launch_bounds__(1024, 4) void gru_l1(
    const float* __restrict__ x,                                    // (4096,2,1024)
    const float* __restrict__ wih1, const float* __restrict__ whh1, // (384,16),(384,128)
    const float* __restrict__ bih1, const float* __restrict__ bhh1,
    half_t* __restrict__ seq1)                                      // (4096,128,128) fp16
{
  __shared__ __align__(16) half_t xl[2][16][XS];     // 33280 B (x chunks, dbuf)
  __shared__ __align__(16) half_t ost[8][16][HS];    // 34816 B h1 ring, slot t&7
  __shared__ __align__(16) f32x4 xpb[2][8][3][64];   // 49152 B xp ring (C/D layout)

  const int tid = threadIdx.x;
  const int lane = tid & 63;
  const int wv = tid >> 6;          // 0..15
  const int q = lane >> 4;
  const int c = lane & 15;
  const bool prod = (wv >= 8);
  const int cw = prod ? (wv - 8) : wv;   // col-tile id 0..7
  const int jc = cw * 16 + c;
  const int s0 = blockIdx.x * 16;

  // zero h1 ring (slot 7 = h1[-1] = 0)
  for (int i = tid; i < 8 * 16 * HS; i += 1024) ((half_t*)ost)[i] = (half_t)0.f;

  // stage x chunk 0 (steps 0..31), all threads, 2 float4s each
#pragma unroll
  for (int p = 0; p < 2; ++p) {
    int idx = tid + p * 1024;            // 0..2047
    int s = idx >> 7, rem = idx & 127, chn = rem >> 6, i4 = rem & 63;
    const float4 v = *(const float4*)(x + (size_t)(s0 + s) * 2048 + chn * 1024 + i4 * 4);
    half4v hv;
    hv[0] = (half_t)v.x; hv[1] = (half_t)v.y; hv[2] = (half_t)v.z; hv[3] = (half_t)v.w;
    *(half4v*)&xl[0][s][(i4 >> 1) * 16 + chn * 8 + (i4 & 1) * 4] = hv;
  }

  // role-shared weights: producer = wih1 (only [g][0], K=16), consumer = whh1
  half8 w[3][4];
  if (prod) {
#pragma unroll
    for (int g = 0; g < 3; ++g) {
      if (q < 2) w[g][0] = ldw8(wih1 + (g * 128 + jc) * 16 + q * 8);
      else       w[g][0] = zero8();
    }
  } else {
#pragma unroll
    for (int g = 0; g < 3; ++g)
#pragma unroll
      for (int kk = 0; kk < 4; ++kk)
        w[g][kk] = ldw8(whh1 + (g * 128 + jc) * 128 + kk * 32 + q * 8);
  }
  const float* bb = prod ? bih1 : bhh1;
  const float b0 = bb[jc], b1 = bb[128 + jc], b2 = bb[256 + jc];

  float h1p[4] = {0.f, 0.f, 0.f, 0.f};
  __syncthreads();

  // prologue: xp[0]
  if (prod) {
    half8 ax = zero8();
    if (q < 2) ax = *(const half8*)&xl[0][c][0 * 16 + q * 8];
    f32x4 ir = {b0, b0, b0, b0}, iz = {b1, b1, b1, b1}, in_ = {b2, b2, b2, b2};
    ir  = mfma16(ax, w[0][0], ir);
    iz  = mfma16(ax, w[1][0], iz);
    in_ = mfma16(ax, w[2][0], in_);
    xpb[0][cw][0][lane] = ir; xpb[0][cw][1][lane] = iz; xpb[0][cw][2][lane] = in_;
  }
  __syncthreads();

  for (int i = 0; i < 128; ++i) {
    if ((i & 7) == 0 && i > 0) {
      // flush previous 8-step group to seq1 (all 16 waves), then resync
      const int g8 = (i >> 3) - 1;
#pragma unroll
      for (int p = 0; p < 2; ++p) {
        int idx = tid + p * 1024;
        int col16 = idx & 15, row = (idx >> 4) & 15, st = idx >> 8;
        f32x4 v = *(const f32x4*)&ost[st][row][col16 * 8];
        *(f32x4*)(seq1 + ((size_t)((s0 + row) * 128 + g8 * 8 + st)) * 128 + col16 * 8) = v;
      }
      __syncthreads();
    }

    if (!prod) {
      // -------- consumer: scan step i --------
      const int rd = (i + 7) & 7;       // slot of h1[i-1]
      half8 f0 = *(const half8*)&ost[rd][c][0 * 32 + q * 8];
      half8 f1 = *(const half8*)&ost[rd][c][1 * 32 + q * 8];
      half8 f2 = *(const half8*)&ost[rd][c][2 * 32 + q * 8];
      half8 f3 = *(const half8*)&ost[rd][c][3 * 32 + q * 8];
      f32x4 xr = xpb[i & 1][cw][0][lane];
      f32x4 xz = xpb[i & 1][cw][1][lane];
      f32x4 xn = xpb[i & 1][cw][2][lane];
      f32x4 hr = {b0, b0, b0, b0}, hz = {b1, b1, b1, b1}, hn = {b2, b2, b2, b2};
      hr = mfma16(f0, w[0][0], hr); hz = mfma16(f0, w[1][0], hz); hn = mfma16(f0, w[2][0], hn);
      hr = mfma16(f1, w[0][1], hr); hz = mfma16(f1, w[1][1], hz); hn = mfma16(f1, w[2][1], hn);
      hr = mfma16(f2, w[0][2], hr); hz = mfma16(f2, w[1][2], hz); hn = mfma16(f2, w[2][2], hn);
      hr = mfma16(f3, w[0][3], hr); hz = mfma16(f3, w[1][3], hz); hn = mfma16(f3, w[2][3], hn);
#pragma unroll
      for (int r = 0; r < 4; ++r) {
        float rg = sigm(xr[r] + hr[r]);
        float zg = sigm(xz[r] + hz[r]);
        float ng = tanh_fast(fmaf(rg, hn[r], xn[r]));
        float hne = fmaf(zg, h1p[r] - ng, ng);
        h1p[r] = hne;
        ost[i & 7][q * 4 + r][jc] = (half_t)hne;
      }
    } else {
      // -------- producer: stage next x chunk (1 op per lane per 8 steps) ----
      if ((i & 7) == 0) {
        int nc = (i >> 5) + 1;
        if (nc < 4) {
          int p = (i >> 3) & 3;
          int idx = (wv - 8) * 64 + lane + p * 512;   // 0..2047
          int s = idx >> 7, rem = idx & 127, chn = rem >> 6, i4 = rem & 63;
          const float4 v = *(const float4*)(x + (size_t)(s0 + s) * 2048 + chn * 1024 + nc * 256 + i4 * 4);
          half4v hv;
          hv[0] = (half_t)v.x; hv[1] = (half_t)v.y; hv[2] = (half_t)v.z; hv[3] = (half_t)v.w;
          *(half4v*)&xl[nc & 1][s][(i4 >> 1) * 16 + chn * 8 + (i4 & 1) * 4] = hv;
        }
      }
      // -------- producer: xp[i+1] --------
      if (i < 127) {
        const int t1 = i + 1;
        half8 ax = zero8();
        if (q < 2) ax = *(const half8*)&xl[(t1 >> 5) & 1][c][(t1 & 31) * 16 + q * 8];
        f32x4 ir = {b0, b0, b0, b0}, iz = {b1, b1, b1, b1}, in_ = {b2, b2, b2, b2};
        ir  = mfma16(ax, w[0][0], ir);
        iz  = mfma16(ax, w[1][0], iz);
        in_ = mfma16(ax, w[2][0], in_);
        xpb[t1 & 1][cw][0][lane] = ir;
        xpb[t1 & 1][cw][1][lane] = iz;
        xpb[t1 & 1][cw][2][lane] = in_;
      }
    }
    __syncthreads();
  }

  // final flush (group 15)
#pragma unroll
  for (int p = 0; p < 2; ++p) {
    int idx = tid + p * 1024;
    int col16 = idx & 15, row = (idx >> 4) & 15, st = idx >> 8;
    f32x4 v = *(const f32x4*)&ost[st][row][col16 * 8];
    *(f32x4*)(seq1 + ((size_t)((s0 + row) * 128 + 15 * 8 + st)) * 128 + col16 * 8) = v;
  }
}

// ============================ Kernel 2: layer 2 + FC =======================
__global__ __launch_bounds__(1024, 4) void gru_l2(
    const half_t* __restrict__ seq1,                                // (4096,128,128) fp16
    const float* __restrict__ wih2, const float* __restrict__ whh2, // (384,128)x2
    const float* __restrict__ bih2, const float* __restrict__ bhh2,
    const float* __restrict__ fcw, const float* __restrict__ fcb,   // (24,128),(24,)
    float* __restrict__ out)                                        // (4096,24)
{
  __shared__ __align__(16) half_t h2b[2][16][HS];    //  8704 B
  __shared__ __align__(16) f32x4 xpb[2][8][3][64];   // 49152 B
  __shared__ float h2f[16][132];                     //  8448 B

  const int tid = threadIdx.x;
  const int lane = tid & 63;
  const int wv = tid >> 6;
  const int q = lane >> 4;
  const int c = lane & 15;
  const bool prod = (wv >= 8);
  const int cw = prod ? (wv - 8) : wv;
  const int jc = cw * 16 + c;
  const int s0 = blockIdx.x * 16;

  for (int i = tid; i < 2 * 16 * HS; i += 1024) ((half_t*)h2b)[i] = (half_t)0.f;

  // role-shared weights: producer = wih2, consumer = whh2 (48 regs each)
  const float* wbase = prod ? wih2 : whh2;
  half8 w[3][4];
#pragma unroll
  for (int g = 0; g < 3; ++g)
#pragma unroll
    for (int kk = 0; kk < 4; ++kk)
      w[g][kk] = ldw8(wbase + (g * 128 + jc) * 128 + kk * 32 + q * 8);
  const float* bb = prod ? bih2 : bhh2;
  const float b0 = bb[jc], b1 = bb[128 + jc], b2 = bb[256 + jc];

  float h2p[4] = {0.f, 0.f, 0.f, 0.f};
  f32x4 buf[2][4];   // producer h1 A-frag prefetch (1-interval lead)

  if (prod) {
    // step-0 frags, compute xp[0]; then kick step-1 frags into buf[1]
#pragma unroll
    for (int kk = 0; kk < 4; ++kk)
      buf[0][kk] = *(const f32x4*)(seq1 + ((size_t)(s0 + c) * 128 + 0) * 128 + kk * 32 + q * 8);
    f32x4 ir = {b0, b0, b0, b0}, iz = {b1, b1, b1, b1}, in_ = {b2, b2, b2, b2};
#pragma unroll
    for (int kk = 0; kk < 4; ++kk) {
      half8 a = __builtin_bit_cast(half8, buf[0][kk]);
      ir  = mfma16(a, w[0][kk], ir);
      iz  = mfma16(a, w[1][kk], iz);
      in_ = mfma16(a, w[2][kk], in_);
    }
    xpb[0][cw][0][lane] = ir; xpb[0][cw][1][lane] = iz; xpb[0][cw][2][lane] = in_;
#pragma unroll
    for (int kk = 0; kk < 4; ++kk)
      buf[1][kk] = *(const f32x4*)(seq1 + ((size_t)(s0 + c) * 128 + 1) * 128 + kk * 32 + q * 8);
  }
  __syncthreads();

  for (int i = 0; i < 128; ++i) {
    if (!prod) {
      // -------- consumer: scan step i --------
      const int rs = (i + 1) & 1;       // slot of h2[i-1]
      half8 f0 = *(const half8*)&h2b[rs][c][0 * 32 + q * 8];
      half8 f1 = *(const half8*)&h2b[rs][c][1 * 32 + q * 8];
      half8 f2 = *(const half8*)&h2b[rs][c][2 * 32 + q * 8];
      half8 f3 = *(const half8*)&h2b[rs][c][3 * 32 + q * 8];
      f32x4 xr = xpb[i & 1][cw][0][lane];
      f32x4 xz = xpb[i & 1][cw][1][lane];
      f32x4 xn = xpb[i & 1][cw][2][lane];
      f32x4 hr = {b0, b0, b0, b0}, hz = {b1, b1, b1, b1}, hn = {b2, b2, b2, b2};
      hr = mfma16(f0, w[0][0], hr); hz = mfma16(f0, w[1][0], hz); hn = mfma16(f0, w[2][0], hn);
      hr = mfma16(f1, w[0][1], hr); hz = mfma16(f1, w[1][1], hz); hn = mfma16(f1, w[2][1], hn);
      hr = mfma16(f2, w[0][2], hr); hz = mfma16(f2, w[1][2], hz); hn = mfma16(f2, w[2][2], hn);
      hr = mfma16(f3, w[0][3], hr); hz = mfma16(f3, w[1][3], hz); hn = mfma16(f3, w[2][3], hn);
#pragma unroll
      for (int r = 0; r < 4; ++r) {
        float rg = sigm(xr[r] + hr[r]);
        float zg = sigm(xz[r] + hz[r]);
        float ng = tanh_fast(fmaf(rg, hn[r], xn[r]));
        float hne = fmaf(zg, h2p[r] - ng, ng);
        h2p[r] = hne;
        h2b[i & 1][q * 4 + r][jc] = (half_t)hne;
      }
    } else if (i < 127) {
      // -------- producer: xp[i+1] from buf[(i+1)&1]; prefetch step i+2 ------
      const int bi = (i + 1) & 1;
      if (i + 2 < 128) {
#pragma unroll
        for (int kk = 0; kk < 4; ++kk)
          buf[bi ^ 1][kk] = *(const f32x4*)(seq1 + ((size_t)(s0 + c) * 128 + (i + 2)) * 128 + kk * 32 + q * 8);
      }
      f32x4 ir = {b0, b0, b0, b0}, iz = {b1, b1, b1, b1}, in_ = {b2, b2, b2, b2};
#pragma unroll
      for (int kk = 0; kk < 4; ++kk) {
        half8 a = __builtin_bit_cast(half8, buf[bi][kk]);
        ir  = mfma16(a, w[0][kk], ir);
        iz  = mfma16(a, w[1][kk], iz);
        in_ = mfma16(a, w[2][kk], in_);
      }
      xpb[bi][cw][0][lane] = ir; xpb[bi][cw][1][lane] = iz; xpb[bi][cw][2][lane] = in_;
    }
    __syncthreads();
  }

  // FC epilogue (fp32)
  if (!prod) {
#pragma unroll
    for (int r = 0; r < 4; ++r) h2f[q * 4 + r][jc] = h2p[r];
  }
  __syncthreads();
  if (tid < 384) {
    const int m = tid & 15;
    const int cls = tid >> 4;
    const float* fw = fcw + cls * 128;
    float acc = fcb[cls];
#pragma unroll 8
    for (int j = 0; j < 128; ++j) acc = fmaf(h2f[m][j], fw[j], acc);
    out[(size_t)(s0 + m) * 24 + cls] = acc;
  }
}

// ===================== Fallback: round-3 fused kernel ======================
__global__ __launch_bounds__(512, 2) void gru_fused(
    const float* __restrict__ x,
    const float* __restrict__ wih1, const float* __restrict__ whh1,
    const float* __restrict__ bih1, const float* __restrict__ bhh1,
    const float* __restrict__ wih2, const float* __restrict__ whh2,
    const float* __restrict__ bih2, const float* __restrict__ bhh2,
    const float* __restrict__ fcw, const float* __restrict__ fcb,
    float* __restrict__ out)
{
  __shared__ __align__(16) half_t xl[16][XS];
  __shared__ __align__(16) half_t h1b[2][16][HS];
  __shared__ __align__(16) half_t h2b[2][16][HS];
  __shared__ float h2f[16][129];

  const int tid = threadIdx.x;
  const int lane = tid & 63;
  const int wv = tid >> 6;
  const int q = lane >> 4;
  const int c = lane & 15;
  const int jc = wv * 16 + c;
  const int s0 = blockIdx.x * 16;

  for (int i = tid; i < 2 * 16 * HS; i += 512) {
    ((half_t*)h1b)[i] = (half_t)0.f;
    ((half_t*)h2b)[i] = (half_t)0.f;
  }

  const float b1r  = bih1[jc]       + bhh1[jc];
  const float b1z  = bih1[128 + jc] + bhh1[128 + jc];
  const float b1in = bih1[256 + jc];
  const float b1hn = bhh1[256 + jc];
  const float b2r  = bih2[jc]       + bhh2[jc];
  const float b2z  = bih2[128 + jc] + bhh2[128 + jc];
  const float b2in = bih2[256 + jc];
  const float b2hn = bhh2[256 + jc];

  half8 wi1r, wi1z, wi1n;
  if (q < 2) {
    wi1r = ldw8(wih1 + (0 * 128 + jc) * 16 + q * 8);
    wi1z = ldw8(wih1 + (1 * 128 + jc) * 16 + q * 8);
    wi1n = ldw8(wih1 + (2 * 128 + jc) * 16 + q * 8);
  } else {
    wi1r = zero8(); wi1z = zero8(); wi1n = zero8();
  }
  half8 wh1r[4], wh1z[4], wh1n[4], wi2r[4], wi2z[4], wi2n[4], wh2r[4], wh2z[4], wh2n[4];
#pragma unroll
  for (int kk = 0; kk < 4; ++kk) {
    const int ko = kk * 32 + q * 8;
    wh1r[kk] = ldw8(whh1 + (0 * 128 + jc) * 128 + ko);
    wh1z[kk] = ldw8(whh1 + (1 * 128 + jc) * 128 + ko);
    wh1n[kk] = ldw8(whh1 + (2 * 128 + jc) * 128 + ko);
    wi2r[kk] = ldw8(wih2 + (0 * 128 + jc) * 128 + ko);
    wi2z[kk] = ldw8(wih2 + (1 * 128 + jc) * 128 + ko);
    wi2n[kk] = ldw8(wih2 + (2 * 128 + jc) * 128 + ko);
    wh2r[kk] = ldw8(whh2 + (0 * 128 + jc) * 128 + ko);
    wh2z[kk] = ldw8(whh2 + (1 * 128 + jc) * 128 + ko);
    wh2n[kk] = ldw8(whh2 + (2 * 128 + jc) * 128 + ko);
  }

  float h1p[4] = {0.f, 0.f, 0.f, 0.f};
  float h2p[4] = {0.f, 0.f, 0.f, 0.f};

  for (int tc = 0; tc < 4; ++tc) {
#pragma unroll
    for (int it = 0; it < 4; ++it) {
      int idx = tid + it * 512;
      int s = idx >> 7;
      int rem = idx & 127;
      int chn = rem >> 6;
      int i4 = rem & 63;
      const float4 v = *(const float4*)(x + (size_t)(s0 + s) * 2048 + chn * 1024 + tc * 256 + i4 * 4);
      half4v hv;
      hv[0] = (half_t)v.x; hv[1] = (half_t)v.y; hv[2] = (half_t)v.z; hv[3] = (half_t)v.w;
      *(half4v*)&xl[s][(i4 >> 1) * 16 + chn * 8 + (i4 & 1) * 4] = hv;
    }
    __syncthreads();

    for (int tt = 0; tt < 32; ++tt) {
      const int i = tc * 32 + tt;
      const int rb = i & 1;
      const int wb = rb ^ 1;

      f32x4 ar  = {b1r, b1r, b1r, b1r};
      f32x4 az  = {b1z, b1z, b1z, b1z};
      f32x4 ain = {b1in, b1in, b1in, b1in};
      f32x4 ahn = {b1hn, b1hn, b1hn, b1hn};
      f32x4 cr  = {b2r, b2r, b2r, b2r};
      f32x4 cz  = {b2z, b2z, b2z, b2z};
      f32x4 cin = {b2in, b2in, b2in, b2in};
      f32x4 chn = {b2hn, b2hn, b2hn, b2hn};

      {
        half8 ax = zero8();
        if (q < 2) ax = *(const half8*)&xl[c][tt * 16 + q * 8];
        ar  = mfma16(ax, wi1r, ar);
        az  = mfma16(ax, wi1z, az);
        ain = mfma16(ax, wi1n, ain);
      }
#pragma unroll
      for (int kk = 0; kk < 4; ++kk) {
        half8 ah = *(const half8*)&h1b[rb][c][kk * 32 + q * 8];
        half8 a2 = *(const half8*)&h2b[rb][c][kk * 32 + q * 8];
        ar  = mfma16(ah, wh1r[kk], ar);
        az  = mfma16(ah, wh1z[kk], az);
        ahn = mfma16(ah, wh1n[kk], ahn);
        cr  = mfma16(ah, wi2r[kk], cr);
        cz  = mfma16(ah, wi2z[kk], cz);
        cin = mfma16(ah, wi2n[kk], cin);
        cr  = mfma16(a2, wh2r[kk], cr);
        cz  = mfma16(a2, wh2z[kk], cz);
        chn = mfma16(a2, wh2n[kk], chn);
      }

#pragma unroll
      for (int r = 0; r < 4; ++r) {
        float rg = sigm(ar[r]);
        float zg = sigm(az[r]);
        float ng = tanh_fast(fmaf(rg, ahn[r], ain[r]));
        float hn = fmaf(zg, h1p[r] - ng, ng);
        h1p[r] = hn;
        h1b[wb][q * 4 + r][jc] = (half_t)hn;
      }
      if (i > 0) {
#pragma unroll
        for (int r = 0; r < 4; ++r) {
          float rg = sigm(cr[r]);
          float zg = sigm(cz[r]);
          float ng = tanh_fast(fmaf(rg, chn[r], cin[r]));
          float hn = fmaf(zg, h2p[r] - ng, ng);
          h2p[r] = hn;
          h2b[wb][q * 4 + r][jc] = (half_t)hn;
        }
      }
      __syncthreads();
    }
  }

  {
    f32x4 cr  = {b2r, b2r, b2r, b2r};
    f32x4 cz  = {b2z, b2z, b2z, b2z};
    f32x4 cin = {b2in, b2in, b2in, b2in};
    f32x4 chn = {b2hn, b2hn, b2hn, b2hn};
#pragma unroll
    for (int kk = 0; kk < 4; ++kk) {
      half8 a1 = *(const half8*)&h1b[0][c][kk * 32 + q * 8];
      half8 a2 = *(const half8*)&h2b[0][c][kk * 32 + q * 8];
      cr  = mfma16(a1, wi2r[kk], cr);
      cz  = mfma16(a1, wi2z[kk], cz);
      cin = mfma16(a1, wi2n[kk], cin);
      cr  = mfma16(a2, wh2r[kk], cr);
      cz  = mfma16(a2, wh2z[kk], cz);
      chn = mfma16(a2, wh2n[kk], chn);
    }
#pragma unroll
    for (int r = 0; r < 4; ++r) {
      float rg = sigm(cr[r]);
      float zg = sigm(cz[r]);
      float ng = tanh_fast(fmaf(rg, chn[r], cin[r]));
      h2p[r] = fmaf(zg, h2p[r] - ng, ng);
    }
  }

#pragma unroll
  for (int r = 0; r < 4; ++r) h2f[q * 4 + r][jc] = h2p[r];
  __syncthreads();
  if (tid < 384) {
    const int m = tid & 15;
    const int cls = tid >> 4;
    const float* fw = fcw + cls * 128;
    float acc = fcb[cls];
#pragma unroll 8
    for (int j = 0; j < 128; ++j) acc = fmaf(h2f[m][j], fw[j], acc);
    out[(size_t)(s0 + m) * 24 + cls] = acc;
  }
}

extern "C" void kernel_launch(void* const* d_in, const int* in_sizes, int n_in,
                              void* d_out, int out_size, void* d_ws, size_t ws_size,
                              hipStream_t stream) {
  (void)in_sizes; (void)n_in; (void)out_size;
  const float* x    = (const float*)d_in[0];
  const float* wih1 = (const float*)d_in[1];
  const float* whh1 = (const float*)d_in[2];
  const float* bih1 = (const float*)d_in[3];
  const float* bhh1 = (const float*)d_in[4];
  const float* wih2 = (const float*)d_in[5];
  const float* whh2 = (const float*)d_in[6];
  const float* bih2 = (const float*)d_in[7];
  const float* bhh2 = (const float*)d_in[8];
  const float* fcw  = (const float*)d_in[9];
  const float* fcb  = (const float*)d_in[10];
  float* outp = (float*)d_out;

  const size_t seq_bytes = (size_t)4096 * 128 * 128 * sizeof(half_t);  // 128 MiB
  if (ws_size >= seq_bytes) {
    half_t* seq1 = (half_t*)d_ws;
    gru_l1<<<dim3(256), dim3(1024), 0, stream>>>(x, wih1, whh1, bih1, bhh1, seq1);
    gru_l2<<<dim3(256), dim3(1024), 0, stream>>>(seq1, wih2, whh2, bih2, bhh2, fcw, fcb, outp);
  } else {
    gru_fused<<<dim3(256), dim3(512), 0, stream>>>(
        x, wih1, whh1, bih1, bhh1, wih2, whh2, bih2, bhh2, fcw, fcb, outp);
  }
}